// Round 12
// baseline (336.164 us; speedup 1.0000x reference)
//
#include <hip/hip_runtime.h>
#include <hip/hip_bf16.h>

typedef unsigned short u16;
typedef unsigned int   u32;
typedef __attribute__((ext_vector_type(8))) short short8;
typedef __attribute__((ext_vector_type(4))) float f32x4;

#define B_   2
#define L_   2048
#define CDIM 384
#define DI   768
#define DXZ  1536
#define DTR  24
#define DS   16
#define NDBC 56
#define NC2  128          // chunks per batch (TC=16)
#define TC   16
#define TL   32
#define EPSV 1e-5f

// converted-weight arena element offsets (bf16)
#define OFFW_WIN  0
#define OFFW_WXP  589824
#define OFFW_WOUT 632832
#define TOTW      927744

__device__ __forceinline__ float bf2f(u16 u) {
    union { u32 i; float f; } v; v.i = ((u32)u) << 16; return v.f;
}
__device__ __forceinline__ u16 f2bf(float f) {
    union { float f; u32 i; } v; v.f = f;
    u32 x = v.i;
    u32 r = (x + 0x7FFFu + ((x >> 16) & 1u)) >> 16;
    return (u16)r;
}

// ---- LN1 (blocks 0..127) + weight conversion (blocks 128..255), one dispatch ----
__global__ __launch_bounds__(256) void ln1_convert(const float* __restrict__ x,
                                                   const float* __restrict__ w,
                                                   const float* __restrict__ bb,
                                                   u16* __restrict__ xn,
                                                   const float* __restrict__ win,
                                                   const float* __restrict__ wxp,
                                                   const float* __restrict__ wout,
                                                   u16* __restrict__ wdst) {
    __shared__ float tile[CDIM][TL + 1];
    __shared__ float red_s[8][TL];
    __shared__ float red_s2[8][TL];
    __shared__ float mu_s[TL], rs_s[TL];
    int tid = threadIdx.x, blk = blockIdx.x;
    if (blk >= 128) {
        int base = (blk - 128) * 256 + tid;
        for (int e = base; e < TOTW; e += 128 * 256) {
            float v;
            if (e < OFFW_WXP)       v = win[e];
            else if (e < OFFW_WOUT) v = wxp[e - OFFW_WXP];
            else                    v = wout[e - OFFW_WOUT];
            wdst[e] = f2bf(v);
        }
        return;
    }
    int b = blk >> 6;
    int l0 = (blk & 63) * TL;
    int cg = tid >> 5, li = tid & 31;
    const float* xp = x + (size_t)b * CDIM * L_ + l0 + li;
    float s = 0.f, s2 = 0.f;
#pragma unroll
    for (int c = cg; c < CDIM; c += 8) {           // coalesced along l
        float v = xp[(size_t)c * L_];
        tile[c][li] = v;
        s += v; s2 += v * v;
    }
    red_s[cg][li] = s; red_s2[cg][li] = s2;
    __syncthreads();
    if (tid < TL) {
        float ts = 0.f, ts2 = 0.f;
#pragma unroll
        for (int g = 0; g < 8; g++) { ts += red_s[g][tid]; ts2 += red_s2[g][tid]; }
        float mu = ts / CDIM;
        float var = ts2 / CDIM - mu * mu;
        mu_s[tid] = mu; rs_s[tid] = rsqrtf(var + EPSV);
    }
    __syncthreads();
    int wv = tid >> 6, lane = tid & 63;
#pragma unroll
    for (int r = 0; r < 8; r++) {
        int l = wv * 8 + r;
        float mu = mu_s[l], rs = rs_s[l];
        u16* op = xn + (size_t)(b * L_ + l0 + l) * CDIM;
#pragma unroll
        for (int j = 0; j < 6; j++) {
            int c = lane + 64 * j;
            float t = (tile[c][l] - mu) * rs * w[c] + bb[c];
            op[c] = f2bf(t);                       // coalesced along c
        }
    }
}

// ---- in_proj GEMM: 128x128 block (2x2 waves of 64x64), K compile-time ----
template<int KN>
__global__ __launch_bounds__(256) void gemm_in(const u16* __restrict__ A,
                                               const u16* __restrict__ Bm,
                                               u16* __restrict__ Cp, int Nn) {
    int wave = threadIdx.x >> 6, lane = threadIdx.x & 63;
    int wm = wave & 1, wn = wave >> 1;
    int m0 = (blockIdx.x * 2 + wm) * 64;
    int n0 = (blockIdx.y * 2 + wn) * 64;
    int r = lane & 15, q = lane >> 4;
    f32x4 acc[4][4];
#pragma unroll
    for (int i = 0; i < 4; i++)
#pragma unroll
        for (int j = 0; j < 4; j++)
#pragma unroll
            for (int g = 0; g < 4; g++) acc[i][j][g] = 0.f;
#pragma unroll
    for (int k0 = 0; k0 < KN; k0 += 32) {
        short8 af[4], bf[4];
        int ka = k0 + q * 8;
#pragma unroll
        for (int i = 0; i < 4; i++) {
            af[i] = *(const short8*)(A + (size_t)(m0 + i * 16 + r) * KN + ka);
            bf[i] = *(const short8*)(Bm + (size_t)(n0 + i * 16 + r) * KN + ka);
        }
#pragma unroll
        for (int i = 0; i < 4; i++)
#pragma unroll
            for (int j = 0; j < 4; j++)
                acc[i][j] = __builtin_amdgcn_mfma_f32_16x16x32_bf16(af[i], bf[j], acc[i][j], 0, 0, 0);
    }
#pragma unroll
    for (int i = 0; i < 4; i++)
#pragma unroll
        for (int j = 0; j < 4; j++) {
            int col = n0 + j * 16 + r;
#pragma unroll
            for (int g = 0; g < 4; g++)
                Cp[(size_t)(m0 + i * 16 + q * 4 + g) * Nn + col] = f2bf(acc[i][j][g]);
        }
}

// ==== FUSED conv+SiLU + x_proj GEMM + scan pass 1.  block=(b,chunk16), 768 thr ====
__global__ __launch_bounds__(768) void convxp_scan1(const u16* __restrict__ xz,
                                                    const float* __restrict__ cw,
                                                    const float* __restrict__ cb,
                                                    const u16* __restrict__ wxpb,
                                                    const float* __restrict__ alogf,
                                                    const float* __restrict__ wdtf,
                                                    const float* __restrict__ bdtf,
                                                    float* __restrict__ dbc,
                                                    float* __restrict__ chA,
                                                    float* __restrict__ chB) {
    __shared__ __align__(16) u16 uS[TC * DI];     // 24576 B
    __shared__ float smR[6][TC][60];              // 23040 B
    __shared__ float dbcS[TC][60];                // 3840 B
    int tid = threadIdx.x;
    int bc = blockIdx.x;                          // b*128 + chunk
    int b = bc >> 7, chunk = bc & 127;
    int t0g = b * L_ + chunk * TC;
    float ur[TC];
    {   // ---- conv + SiLU, thread = d ----
        int d = tid;
        float4 c4 = ((const float4*)cw)[d];
        float bias = cb[d];
        float w0, w1, w2;
        if (chunk == 0) { w0 = w1 = w2 = 0.f; }
        else {
            w0 = bf2f(xz[(size_t)(t0g - 3) * DXZ + d]);
            w1 = bf2f(xz[(size_t)(t0g - 2) * DXZ + d]);
            w2 = bf2f(xz[(size_t)(t0g - 1) * DXZ + d]);
        }
#pragma unroll
        for (int t = 0; t < TC; t++) {
            float cur = bf2f(xz[(size_t)(t0g + t) * DXZ + d]);
            float acc = bias + w0 * c4.x + w1 * c4.y + w2 * c4.z + cur * c4.w;
            float sg = 1.f / (1.f + __expf(-acc));
            ur[t] = acc * sg;
            uS[t * DI + (d ^ ((t & 7) << 3))] = f2bf(ur[t]);
            w0 = w1; w1 = w2; w2 = cur;
        }
    }
    __syncthreads();
    {   // ---- x_proj GEMM: waves 0..5, K-slice 128 each ----
        int wave = tid >> 6, lane = tid & 63;
        int r = lane & 15, q = lane >> 4;
        if (wave < 6) {
            f32x4 acc[4];
#pragma unroll
            for (int j = 0; j < 4; j++)
#pragma unroll
                for (int g = 0; g < 4; g++) acc[j][g] = 0.f;
            short8 zf;
#pragma unroll
            for (int e = 0; e < 8; e++) zf[e] = 0;
            int kb = wave * 128;
#pragma unroll
            for (int k0 = 0; k0 < 128; k0 += 32) {
                int ka = kb + k0 + q * 8;
                short8 af = *(const short8*)(&uS[r * DI + (ka ^ ((r & 7) << 3))]);
                short8 bfv[4];
#pragma unroll
                for (int j = 0; j < 4; j++) {
                    int n = j * 16 + r;
                    bfv[j] = (n < NDBC) ? *(const short8*)(wxpb + (size_t)n * DI + ka) : zf;
                }
#pragma unroll
                for (int j = 0; j < 4; j++)
                    acc[j] = __builtin_amdgcn_mfma_f32_16x16x32_bf16(af, bfv[j], acc[j], 0, 0, 0);
            }
#pragma unroll
            for (int j = 0; j < 4; j++) {
                int col = j * 16 + r;
                if (col < NDBC) {
#pragma unroll
                    for (int g = 0; g < 4; g++)
                        smR[wave][q * 4 + g][col] = acc[j][g];
                }
            }
        }
    }
    __syncthreads();
    for (int e = tid; e < TC * NDBC; e += 768) {   // reduce 6 K-slices
        int row = e / NDBC, col = e - row * NDBC;
        float v = 0.f;
#pragma unroll
        for (int ks = 0; ks < 6; ks++) v += smR[ks][row][col];
        dbcS[row][col] = v;
        dbc[(size_t)(t0g + row) * NDBC + col] = v;   // pass 2 stages this
    }
    __syncthreads();
    {   // ---- scan pass 1, thread = d ----
        int d = tid;
        float a[DS], ap[DS], bv[DS], wdtv[DTR];
#pragma unroll
        for (int s = 0; s < DS; s++) { a[s] = -__expf(alogf[d * DS + s]); ap[s] = 1.f; bv[s] = 0.f; }
#pragma unroll
        for (int k = 0; k < DTR; k++) wdtv[k] = wdtf[d * DTR + k];
        float bd = bdtf[d];
#pragma unroll 2
        for (int t = 0; t < TC; t++) {
            float acc = bd;
#pragma unroll
            for (int k = 0; k < DTR; k++) acc += dbcS[t][k] * wdtv[k];
            float dd = (acc > 20.f) ? acc : __logf(1.f + __expf(acc));
            float du = dd * ur[t];
#pragma unroll
            for (int s = 0; s < DS; s++) {
                float dA = __expf(dd * a[s]);
                bv[s] = dA * bv[s] + du * dbcS[t][DTR + s];
                ap[s] *= dA;
            }
        }
        float* pa = chA + (size_t)bc * DS * DI + d;
        float* pb = chB + (size_t)bc * DS * DI + d;
#pragma unroll
        for (int s = 0; s < DS; s++) { pa[(size_t)s * DI] = ap[s]; pb[(size_t)s * DI] = bv[s]; }
    }
}

// -------- scan mid: per (b,slot) scalar chain over 128 chunks, coalesced --------
__global__ __launch_bounds__(256) void scan_mid(const float* __restrict__ chA,
                                                const float* __restrict__ chB,
                                                float* __restrict__ hin) {
    int idx = blockIdx.x * 256 + threadIdx.x;   // 0..24575
    int b = idx / (DI * DS);
    int rem = idx - b * (DI * DS);
    float h = 0.f;
#pragma unroll 8
    for (int c = 0; c < NC2; c++) {
        size_t off = ((size_t)(b * NC2 + c) * DI) * DS + rem;
        hin[off] = h;
        h = chA[off] * h + chB[off];
    }
}

// ==== FUSED conv-replay + scan pass 2 + out_proj GEMM + LN2, PAIR-SPLIT ====
// grid 512: blockIdx = (bc<<1)|half. Both halves duplicate conv+scan (latency-
// bound, identical values); each half owns 8 of 16 t-rows for GEMM/LN2/IO.
// -> 2 blocks/CU: one block's scan VALU overlaps the other's staging/GEMM.
__global__ __launch_bounds__(768, 6) void scan2_out_ln2(const u16* __restrict__ xz,
                                                        const float* __restrict__ cw,
                                                        const float* __restrict__ cb,
                                                        const float* __restrict__ dbc,
                                                        const float* __restrict__ alogf,
                                                        const float* __restrict__ wdtf,
                                                        const float* __restrict__ bdtf,
                                                        const float* __restrict__ hin,
                                                        const float* __restrict__ Dwf,
                                                        const u16* __restrict__ woutb,
                                                        const float* __restrict__ x,
                                                        const float* __restrict__ w2,
                                                        const float* __restrict__ b2,
                                                        float* __restrict__ out) {
    __shared__ __align__(16) char uni[TC * DI * 2];    // ymS 24576B; xT (8x388 f32) overlays
    __shared__ float smO[8][388];                      // 12416 B
    __shared__ float dbcS[TC][60];                     // 3840 B
    __shared__ float mu_s[8], rs_s[8];
    u16* ymS = (u16*)uni;
    float (*xT)[388] = (float(*)[388])uni;
    int tid = threadIdx.x;
    int bc2 = blockIdx.x;
    int bc = bc2 >> 1, half = bc2 & 1;
    int b = bc >> 7, chunk = bc & 127;
    int t0g = b * L_ + chunk * TC;
    int lrow0 = chunk * TC + half * 8;                 // global l of this half's first row
    for (int e = tid; e < TC * NDBC; e += 768) {       // stage dbc tile (full, both halves)
        int row = e / NDBC, col = e - row * NDBC;
        dbcS[row][col] = dbc[(size_t)(t0g + row) * NDBC + col];
    }
    float ur[TC];
    {   // ---- conv replay (bit-identical order to pass 1; duplicated in pair) ----
        int d = tid;
        float4 c4 = ((const float4*)cw)[d];
        float bias = cb[d];
        float w0, w1, w2c;
        if (chunk == 0) { w0 = w1 = w2c = 0.f; }
        else {
            w0  = bf2f(xz[(size_t)(t0g - 3) * DXZ + d]);
            w1  = bf2f(xz[(size_t)(t0g - 2) * DXZ + d]);
            w2c = bf2f(xz[(size_t)(t0g - 1) * DXZ + d]);
        }
#pragma unroll
        for (int t = 0; t < TC; t++) {
            float cur = bf2f(xz[(size_t)(t0g + t) * DXZ + d]);
            float acc = bias + w0 * c4.x + w1 * c4.y + w2c * c4.z + cur * c4.w;
            float sg = 1.f / (1.f + __expf(-acc));
            ur[t] = acc * sg;
            w0 = w1; w1 = w2c; w2c = cur;
        }
    }
    __syncthreads();
    {   // ---- scan pass 2, thread = d (full 16 t, duplicated in pair) ----
        int d = tid;
        float a[DS], h[DS], wdtv[DTR];
#pragma unroll
        for (int s = 0; s < DS; s++) a[s] = -__expf(alogf[d * DS + s]);
#pragma unroll
        for (int k = 0; k < DTR; k++) wdtv[k] = wdtf[d * DTR + k];
        float bd = bdtf[d];
        const float* hp = hin + (size_t)bc * DS * DI + d;
#pragma unroll
        for (int s = 0; s < DS; s++) h[s] = hp[(size_t)s * DI];   // coalesced
        float dD = Dwf[d];
#pragma unroll 2
        for (int t = 0; t < TC; t++) {
            float acc = bd;
#pragma unroll
            for (int k = 0; k < DTR; k++) acc += dbcS[t][k] * wdtv[k];
            float dd = (acc > 20.f) ? acc : __logf(1.f + __expf(acc));
            float uu = ur[t];
            float du = dd * uu;
            float y = 0.f;
#pragma unroll
            for (int s = 0; s < DS; s++) {
                float dA = __expf(dd * a[s]);
                h[s] = dA * h[s] + du * dbcS[t][DTR + s];
                y += h[s] * dbcS[t][DTR + DS + s];
            }
            float z = bf2f(xz[(size_t)(t0g + t) * DXZ + DI + d]);
            float sg = 1.f / (1.f + __expf(-z));
            ymS[t * DI + (d ^ ((t & 7) << 3))] = f2bf((y + uu * dD) * (z * sg));
        }
    }
    __syncthreads();
    {   // ---- out_proj GEMM from LDS: waves 0..5, n-tile 64, this half's 8 rows ----
        int wave = tid >> 6, lane = tid & 63;
        int r = lane & 15, q = lane >> 4;
        if (wave < 6) {
            int n0 = wave * 64;
            f32x4 acc[4];
#pragma unroll
            for (int j = 0; j < 4; j++)
#pragma unroll
                for (int g = 0; g < 4; g++) acc[j][g] = 0.f;
            short8 zf;
#pragma unroll
            for (int e = 0; e < 8; e++) zf[e] = 0;
            int trow = half * 8 + r;                   // ym t-row for A lane r (r<8 valid)
            int xw = (trow & 7) << 3;
#pragma unroll
            for (int k0 = 0; k0 < DI; k0 += 32) {
                int ka = k0 + q * 8;
                short8 af = (r < 8) ? *(const short8*)(&ymS[trow * DI + (ka ^ xw)]) : zf;
                short8 bfv[4];
#pragma unroll
                for (int j = 0; j < 4; j++)
                    bfv[j] = *(const short8*)(woutb + (size_t)(n0 + j * 16 + r) * DI + ka);
#pragma unroll
                for (int j = 0; j < 4; j++)
                    acc[j] = __builtin_amdgcn_mfma_f32_16x16x32_bf16(af, bfv[j], acc[j], 0, 0, 0);
            }
            if (q < 2) {                               // C rows 0..7 only (valid A rows)
#pragma unroll
                for (int j = 0; j < 4; j++) {
                    int col = n0 + j * 16 + r;
#pragma unroll
                    for (int g = 0; g < 4; g++)
                        smO[q * 4 + g][col] = acc[j][g];
                }
            }
        }
    }
    __syncthreads();
    // ---- stage x tile (this half's 8 rows) over dead ymS; add into smO ----
#pragma unroll
    for (int ii = 0; ii < 4; ii++) {
        int e = tid + ii * 768;                        // 3072 = 384c x 8l
        int c = e >> 3, l = e & 7;
        float xv = x[(size_t)b * CDIM * L_ + (size_t)c * L_ + lrow0 + l];
        xT[l][c] = xv + smO[l][c];
    }
    __syncthreads();
    {   // ---- LN2 row reduce: waves 0..7 cover 8 rows ----
        int wave = tid >> 6, lane = tid & 63;
        if (wave < 8) {
            int row = wave;
            float s = 0.f, s2 = 0.f;
#pragma unroll
            for (int j = 0; j < 6; j++) {
                float t = xT[row][lane + 64 * j];
                s += t; s2 += t * t;
            }
#pragma unroll
            for (int off = 32; off > 0; off >>= 1) { s += __shfl_xor(s, off); s2 += __shfl_xor(s2, off); }
            if (lane == 0) {
                float mu = s / CDIM;
                float var = s2 / CDIM - mu * mu;
                mu_s[row] = mu; rs_s[row] = rsqrtf(var + EPSV);
            }
        }
    }
    __syncthreads();
#pragma unroll
    for (int ii = 0; ii < 4; ii++) {
        int e = tid + ii * 768;
        int c = e >> 3, l = e & 7;
        float t = (xT[l][c] - mu_s[l]) * rs_s[l] * w2[c] + b2[c];
        out[(size_t)b * CDIM * L_ + (size_t)c * L_ + lrow0 + l] = t;
    }
}

extern "C" void kernel_launch(void* const* d_in, const int* in_sizes, int n_in,
                              void* d_out, int out_size, void* d_ws, size_t ws_size,
                              hipStream_t stream) {
    const float* x    = (const float*)d_in[0];
    const float* ln1w = (const float*)d_in[1];
    const float* ln1b = (const float*)d_in[2];
    const float* ln2w = (const float*)d_in[3];
    const float* ln2b = (const float*)d_in[4];
    const float* win  = (const float*)d_in[5];   // (1536, 384)
    const float* cw   = (const float*)d_in[6];   // (768, 1, 4)
    const float* cb   = (const float*)d_in[7];   // (768,)
    const float* wxp  = (const float*)d_in[8];   // (56, 768)
    const float* wdt  = (const float*)d_in[9];   // (768, 24)
    const float* bdt  = (const float*)d_in[10];  // (768,)
    const float* alog = (const float*)d_in[11];  // (768, 16)
    const float* Dw   = (const float*)d_in[12];  // (768,)
    const float* wout = (const float*)d_in[13];  // (384, 768)

    char* ws = (char*)d_ws;
    u16*   wbf    = (u16*)(ws + 0);            // 927744 bf16
    u16*   win_b  = wbf + OFFW_WIN;
    u16*   wxp_b  = wbf + OFFW_WXP;
    u16*   wout_b = wbf + OFFW_WOUT;
    u16*   xn     = (u16*)(ws + 1855488);      // 4096*384 bf16
    u16*   xz     = (u16*)(ws + 5001216);      // 4096*1536 bf16
    float* dbc    = (float*)(ws + 17584128);   // 4096*56 f32
    float* chA    = (float*)(ws + 18501632);   // 256 bc * 16*768 f32 (s-major per bc)
    float* chB    = (float*)(ws + 31084544);
    float* hin    = (float*)(ws + 43667456);

    ln1_convert<<<dim3(256), 256, 0, stream>>>(x, ln1w, ln1b, xn, win, wxp, wout, wbf);
    gemm_in<384><<<dim3(32, 12), 256, 0, stream>>>(xn, win_b, xz, DXZ);
    convxp_scan1<<<dim3(256), 768, 0, stream>>>(xz, cw, cb, wxp_b, alog, wdt, bdt, dbc, chA, chB);
    scan_mid<<<96, 256, 0, stream>>>(chA, chB, hin);
    scan2_out_ln2<<<dim3(512), 768, 0, stream>>>(xz, cw, cb, dbc, alog, wdt, bdt, hin, Dw,
                                                 wout_b, x, ln2w, ln2b, (float*)d_out);
}

// Round 13
// 203.126 us; speedup vs baseline: 1.6550x; 1.6550x over previous
//
#include <hip/hip_runtime.h>
#include <hip/hip_bf16.h>

typedef unsigned short u16;
typedef unsigned int   u32;
typedef __attribute__((ext_vector_type(8))) short short8;
typedef __attribute__((ext_vector_type(4))) float f32x4;

#define B_   2
#define L_   2048
#define CDIM 384
#define DI   768
#define DXZ  1536
#define DTR  24
#define DS   16
#define NDBC 56
#define NC2  128          // chunks per batch (TC=16)
#define TC   16
#define TL   32
#define EPSV 1e-5f

// converted-weight arena element offsets (bf16)
#define OFFW_WIN  0
#define OFFW_WXP  589824
#define OFFW_WOUT 632832
#define TOTW      927744

__device__ __forceinline__ float bf2f(u16 u) {
    union { u32 i; float f; } v; v.i = ((u32)u) << 16; return v.f;
}
__device__ __forceinline__ u16 f2bf(float f) {
    union { float f; u32 i; } v; v.f = f;
    u32 x = v.i;
    u32 r = (x + 0x7FFFu + ((x >> 16) & 1u)) >> 16;
    return (u16)r;
}

// ---- LN1 (blocks 0..127) + weight conversion (blocks 128..255), one dispatch ----
__global__ __launch_bounds__(256) void ln1_convert(const float* __restrict__ x,
                                                   const float* __restrict__ w,
                                                   const float* __restrict__ bb,
                                                   u16* __restrict__ xn,
                                                   const float* __restrict__ win,
                                                   const float* __restrict__ wxp,
                                                   const float* __restrict__ wout,
                                                   u16* __restrict__ wdst) {
    __shared__ float tile[CDIM][TL + 1];
    __shared__ float red_s[8][TL];
    __shared__ float red_s2[8][TL];
    __shared__ float mu_s[TL], rs_s[TL];
    int tid = threadIdx.x, blk = blockIdx.x;
    if (blk >= 128) {
        int base = (blk - 128) * 256 + tid;
        for (int e = base; e < TOTW; e += 128 * 256) {
            float v;
            if (e < OFFW_WXP)       v = win[e];
            else if (e < OFFW_WOUT) v = wxp[e - OFFW_WXP];
            else                    v = wout[e - OFFW_WOUT];
            wdst[e] = f2bf(v);
        }
        return;
    }
    int b = blk >> 6;
    int l0 = (blk & 63) * TL;
    int cg = tid >> 5, li = tid & 31;
    const float* xp = x + (size_t)b * CDIM * L_ + l0 + li;
    float s = 0.f, s2 = 0.f;
#pragma unroll
    for (int c = cg; c < CDIM; c += 8) {           // coalesced along l
        float v = xp[(size_t)c * L_];
        tile[c][li] = v;
        s += v; s2 += v * v;
    }
    red_s[cg][li] = s; red_s2[cg][li] = s2;
    __syncthreads();
    if (tid < TL) {
        float ts = 0.f, ts2 = 0.f;
#pragma unroll
        for (int g = 0; g < 8; g++) { ts += red_s[g][tid]; ts2 += red_s2[g][tid]; }
        float mu = ts / CDIM;
        float var = ts2 / CDIM - mu * mu;
        mu_s[tid] = mu; rs_s[tid] = rsqrtf(var + EPSV);
    }
    __syncthreads();
    int wv = tid >> 6, lane = tid & 63;
#pragma unroll
    for (int r = 0; r < 8; r++) {
        int l = wv * 8 + r;
        float mu = mu_s[l], rs = rs_s[l];
        u16* op = xn + (size_t)(b * L_ + l0 + l) * CDIM;
#pragma unroll
        for (int j = 0; j < 6; j++) {
            int c = lane + 64 * j;
            float t = (tile[c][l] - mu) * rs * w[c] + bb[c];
            op[c] = f2bf(t);                       // coalesced along c
        }
    }
}

// ---- in_proj GEMM: 128x128 block (2x2 waves of 64x64), K compile-time ----
template<int KN>
__global__ __launch_bounds__(256) void gemm_in(const u16* __restrict__ A,
                                               const u16* __restrict__ Bm,
                                               u16* __restrict__ Cp, int Nn) {
    int wave = threadIdx.x >> 6, lane = threadIdx.x & 63;
    int wm = wave & 1, wn = wave >> 1;
    int m0 = (blockIdx.x * 2 + wm) * 64;
    int n0 = (blockIdx.y * 2 + wn) * 64;
    int r = lane & 15, q = lane >> 4;
    f32x4 acc[4][4];
#pragma unroll
    for (int i = 0; i < 4; i++)
#pragma unroll
        for (int j = 0; j < 4; j++)
#pragma unroll
            for (int g = 0; g < 4; g++) acc[i][j][g] = 0.f;
#pragma unroll
    for (int k0 = 0; k0 < KN; k0 += 32) {
        short8 af[4], bf[4];
        int ka = k0 + q * 8;
#pragma unroll
        for (int i = 0; i < 4; i++) {
            af[i] = *(const short8*)(A + (size_t)(m0 + i * 16 + r) * KN + ka);
            bf[i] = *(const short8*)(Bm + (size_t)(n0 + i * 16 + r) * KN + ka);
        }
#pragma unroll
        for (int i = 0; i < 4; i++)
#pragma unroll
            for (int j = 0; j < 4; j++)
                acc[i][j] = __builtin_amdgcn_mfma_f32_16x16x32_bf16(af[i], bf[j], acc[i][j], 0, 0, 0);
    }
#pragma unroll
    for (int i = 0; i < 4; i++)
#pragma unroll
        for (int j = 0; j < 4; j++) {
            int col = n0 + j * 16 + r;
#pragma unroll
            for (int g = 0; g < 4; g++)
                Cp[(size_t)(m0 + i * 16 + q * 4 + g) * Nn + col] = f2bf(acc[i][j][g]);
        }
}

// ==== FUSED conv+SiLU + x_proj GEMM + scan pass 1.  block=(b,chunk16), 768 thr ====
__global__ __launch_bounds__(768) void convxp_scan1(const u16* __restrict__ xz,
                                                    const float* __restrict__ cw,
                                                    const float* __restrict__ cb,
                                                    const u16* __restrict__ wxpb,
                                                    const float* __restrict__ alogf,
                                                    const float* __restrict__ wdtf,
                                                    const float* __restrict__ bdtf,
                                                    float* __restrict__ dbc,
                                                    float* __restrict__ chA,
                                                    float* __restrict__ chB) {
    __shared__ __align__(16) u16 uS[TC * DI];     // 24576 B
    __shared__ float smR[6][TC][60];              // 23040 B
    __shared__ float dbcS[TC][60];                // 3840 B
    int tid = threadIdx.x;
    int bc = blockIdx.x;                          // b*128 + chunk
    int b = bc >> 7, chunk = bc & 127;
    int t0g = b * L_ + chunk * TC;
    float ur[TC];
    {   // ---- conv + SiLU, thread = d ----
        int d = tid;
        float4 c4 = ((const float4*)cw)[d];
        float bias = cb[d];
        float w0, w1, w2;
        if (chunk == 0) { w0 = w1 = w2 = 0.f; }
        else {
            w0 = bf2f(xz[(size_t)(t0g - 3) * DXZ + d]);
            w1 = bf2f(xz[(size_t)(t0g - 2) * DXZ + d]);
            w2 = bf2f(xz[(size_t)(t0g - 1) * DXZ + d]);
        }
#pragma unroll
        for (int t = 0; t < TC; t++) {
            float cur = bf2f(xz[(size_t)(t0g + t) * DXZ + d]);
            float acc = bias + w0 * c4.x + w1 * c4.y + w2 * c4.z + cur * c4.w;
            float sg = 1.f / (1.f + __expf(-acc));
            ur[t] = acc * sg;
            uS[t * DI + (d ^ ((t & 7) << 3))] = f2bf(ur[t]);
            w0 = w1; w1 = w2; w2 = cur;
        }
    }
    __syncthreads();
    {   // ---- x_proj GEMM: waves 0..5, K-slice 128 each ----
        int wave = tid >> 6, lane = tid & 63;
        int r = lane & 15, q = lane >> 4;
        if (wave < 6) {
            f32x4 acc[4];
#pragma unroll
            for (int j = 0; j < 4; j++)
#pragma unroll
                for (int g = 0; g < 4; g++) acc[j][g] = 0.f;
            short8 zf;
#pragma unroll
            for (int e = 0; e < 8; e++) zf[e] = 0;
            int kb = wave * 128;
#pragma unroll
            for (int k0 = 0; k0 < 128; k0 += 32) {
                int ka = kb + k0 + q * 8;
                short8 af = *(const short8*)(&uS[r * DI + (ka ^ ((r & 7) << 3))]);
                short8 bfv[4];
#pragma unroll
                for (int j = 0; j < 4; j++) {
                    int n = j * 16 + r;
                    bfv[j] = (n < NDBC) ? *(const short8*)(wxpb + (size_t)n * DI + ka) : zf;
                }
#pragma unroll
                for (int j = 0; j < 4; j++)
                    acc[j] = __builtin_amdgcn_mfma_f32_16x16x32_bf16(af, bfv[j], acc[j], 0, 0, 0);
            }
#pragma unroll
            for (int j = 0; j < 4; j++) {
                int col = j * 16 + r;
                if (col < NDBC) {
#pragma unroll
                    for (int g = 0; g < 4; g++)
                        smR[wave][q * 4 + g][col] = acc[j][g];
                }
            }
        }
    }
    __syncthreads();
    for (int e = tid; e < TC * NDBC; e += 768) {   // reduce 6 K-slices
        int row = e / NDBC, col = e - row * NDBC;
        float v = 0.f;
#pragma unroll
        for (int ks = 0; ks < 6; ks++) v += smR[ks][row][col];
        dbcS[row][col] = v;
        dbc[(size_t)(t0g + row) * NDBC + col] = v;   // pass 2 stages this
    }
    __syncthreads();
    {   // ---- scan pass 1, thread = d ----
        int d = tid;
        float a[DS], ap[DS], bv[DS], wdtv[DTR];
#pragma unroll
        for (int s = 0; s < DS; s++) { a[s] = -__expf(alogf[d * DS + s]); ap[s] = 1.f; bv[s] = 0.f; }
#pragma unroll
        for (int k = 0; k < DTR; k++) wdtv[k] = wdtf[d * DTR + k];
        float bd = bdtf[d];
#pragma unroll 2
        for (int t = 0; t < TC; t++) {
            float acc = bd;
#pragma unroll
            for (int k = 0; k < DTR; k++) acc += dbcS[t][k] * wdtv[k];
            float dd = (acc > 20.f) ? acc : __logf(1.f + __expf(acc));
            float du = dd * ur[t];
#pragma unroll
            for (int s = 0; s < DS; s++) {
                float dA = __expf(dd * a[s]);
                bv[s] = dA * bv[s] + du * dbcS[t][DTR + s];
                ap[s] *= dA;
            }
        }
        float* pa = chA + (size_t)bc * DS * DI + d;
        float* pb = chB + (size_t)bc * DS * DI + d;
#pragma unroll
        for (int s = 0; s < DS; s++) { pa[(size_t)s * DI] = ap[s]; pb[(size_t)s * DI] = bv[s]; }
    }
}

// -------- scan mid: per (b,slot) scalar chain over 128 chunks, coalesced --------
__global__ __launch_bounds__(256) void scan_mid(const float* __restrict__ chA,
                                                const float* __restrict__ chB,
                                                float* __restrict__ hin) {
    int idx = blockIdx.x * 256 + threadIdx.x;   // 0..24575
    int b = idx / (DI * DS);
    int rem = idx - b * (DI * DS);
    float h = 0.f;
#pragma unroll 8
    for (int c = 0; c < NC2; c++) {
        size_t off = ((size_t)(b * NC2 + c) * DI) * DS + rem;
        hin[off] = h;
        h = chA[off] * h + chB[off];
    }
}

// ==== FUSED conv-replay + scan pass 2 + out_proj GEMM + LN2.  block=(b,chunk16) ====
__global__ __launch_bounds__(768) void scan2_out_ln2(const u16* __restrict__ xz,
                                                     const float* __restrict__ cw,
                                                     const float* __restrict__ cb,
                                                     const float* __restrict__ dbc,
                                                     const float* __restrict__ alogf,
                                                     const float* __restrict__ wdtf,
                                                     const float* __restrict__ bdtf,
                                                     const float* __restrict__ hin,
                                                     const float* __restrict__ Dwf,
                                                     const u16* __restrict__ woutb,
                                                     const float* __restrict__ x,
                                                     const float* __restrict__ w2,
                                                     const float* __restrict__ b2,
                                                     float* __restrict__ out) {
    __shared__ __align__(16) char uni[TC * 388 * 4];   // ymS (24576B) then xT (24832B)
    __shared__ float smO[TC][388];                     // 24832 B
    __shared__ float dbcS[TC][60];                     // 3840 B
    __shared__ float mu_s[TC], rs_s[TC];
    u16* ymS = (u16*)uni;
    float (*xT)[388] = (float(*)[388])uni;
    int tid = threadIdx.x;
    int bc = blockIdx.x;
    int b = bc >> 7, chunk = bc & 127;
    int t0g = b * L_ + chunk * TC;
    for (int e = tid; e < TC * NDBC; e += 768) {       // stage dbc tile
        int row = e / NDBC, col = e - row * NDBC;
        dbcS[row][col] = dbc[(size_t)(t0g + row) * NDBC + col];
    }
    float ur[TC];
    {   // ---- conv replay (bit-identical order to pass 1) ----
        int d = tid;
        float4 c4 = ((const float4*)cw)[d];
        float bias = cb[d];
        float w0, w1, w2c;
        if (chunk == 0) { w0 = w1 = w2c = 0.f; }
        else {
            w0  = bf2f(xz[(size_t)(t0g - 3) * DXZ + d]);
            w1  = bf2f(xz[(size_t)(t0g - 2) * DXZ + d]);
            w2c = bf2f(xz[(size_t)(t0g - 1) * DXZ + d]);
        }
#pragma unroll
        for (int t = 0; t < TC; t++) {
            float cur = bf2f(xz[(size_t)(t0g + t) * DXZ + d]);
            float acc = bias + w0 * c4.x + w1 * c4.y + w2c * c4.z + cur * c4.w;
            float sg = 1.f / (1.f + __expf(-acc));
            ur[t] = acc * sg;
            w0 = w1; w1 = w2c; w2c = cur;
        }
    }
    __syncthreads();
    {   // ---- scan pass 2, thread = d ----
        int d = tid;
        float a[DS], h[DS], wdtv[DTR];
#pragma unroll
        for (int s = 0; s < DS; s++) a[s] = -__expf(alogf[d * DS + s]);
#pragma unroll
        for (int k = 0; k < DTR; k++) wdtv[k] = wdtf[d * DTR + k];
        float bd = bdtf[d];
        const float* hp = hin + (size_t)bc * DS * DI + d;
#pragma unroll
        for (int s = 0; s < DS; s++) h[s] = hp[(size_t)s * DI];   // coalesced
        float dD = Dwf[d];
#pragma unroll 2
        for (int t = 0; t < TC; t++) {
            float acc = bd;
#pragma unroll
            for (int k = 0; k < DTR; k++) acc += dbcS[t][k] * wdtv[k];
            float dd = (acc > 20.f) ? acc : __logf(1.f + __expf(acc));
            float uu = ur[t];
            float du = dd * uu;
            float y = 0.f;
#pragma unroll
            for (int s = 0; s < DS; s++) {
                float dA = __expf(dd * a[s]);
                h[s] = dA * h[s] + du * dbcS[t][DTR + s];
                y += h[s] * dbcS[t][DTR + DS + s];
            }
            float z = bf2f(xz[(size_t)(t0g + t) * DXZ + DI + d]);
            float sg = 1.f / (1.f + __expf(-z));
            ymS[t * DI + (d ^ ((t & 7) << 3))] = f2bf((y + uu * dD) * (z * sg));
        }
    }
    __syncthreads();
    {   // ---- out_proj GEMM from LDS: waves 0..5, n-tile 64 each, K=768 ----
        int wave = tid >> 6, lane = tid & 63;
        int r = lane & 15, q = lane >> 4;
        if (wave < 6) {
            int n0 = wave * 64;
            f32x4 acc[4];
#pragma unroll
            for (int j = 0; j < 4; j++)
#pragma unroll
                for (int g = 0; g < 4; g++) acc[j][g] = 0.f;
            int xw = (r & 7) << 3;
#pragma unroll
            for (int k0 = 0; k0 < DI; k0 += 32) {
                int ka = k0 + q * 8;
                short8 af = *(const short8*)(&ymS[r * DI + (ka ^ xw)]);
                short8 bfv[4];
#pragma unroll
                for (int j = 0; j < 4; j++)
                    bfv[j] = *(const short8*)(woutb + (size_t)(n0 + j * 16 + r) * DI + ka);
#pragma unroll
                for (int j = 0; j < 4; j++)
                    acc[j] = __builtin_amdgcn_mfma_f32_16x16x32_bf16(af, bfv[j], acc[j], 0, 0, 0);
            }
#pragma unroll
            for (int j = 0; j < 4; j++) {
                int col = n0 + j * 16 + r;
#pragma unroll
                for (int g = 0; g < 4; g++)
                    smO[q * 4 + g][col] = acc[j][g];
            }
        }
    }
    __syncthreads();
    // ---- stage x tile over dead ymS; add into smO ----
#pragma unroll
    for (int ii = 0; ii < 8; ii++) {
        int e = tid + ii * 768;                        // 6144 = 384c x 16l
        int c = e >> 4, l = e & 15;
        float xv = x[(size_t)b * CDIM * L_ + (size_t)c * L_ + chunk * TC + l];
        xT[l][c] = xv + smO[l][c];
    }
    __syncthreads();
    {   // ---- LN2 row reduce: 12 waves cover 16 rows (stride 12) ----
        int wave = tid >> 6, lane = tid & 63;
        for (int row = wave; row < TC; row += 12) {
            float s = 0.f, s2 = 0.f;
#pragma unroll
            for (int j = 0; j < 6; j++) {
                float t = xT[row][lane + 64 * j];
                s += t; s2 += t * t;
            }
#pragma unroll
            for (int off = 32; off > 0; off >>= 1) { s += __shfl_xor(s, off); s2 += __shfl_xor(s2, off); }
            if (lane == 0) {
                float mu = s / CDIM;
                float var = s2 / CDIM - mu * mu;
                mu_s[row] = mu; rs_s[row] = rsqrtf(var + EPSV);
            }
        }
    }
    __syncthreads();
#pragma unroll
    for (int ii = 0; ii < 8; ii++) {
        int e = tid + ii * 768;
        int c = e >> 4, l = e & 15;
        float t = (xT[l][c] - mu_s[l]) * rs_s[l] * w2[c] + b2[c];
        out[(size_t)b * CDIM * L_ + (size_t)c * L_ + chunk * TC + l] = t;
    }
}

extern "C" void kernel_launch(void* const* d_in, const int* in_sizes, int n_in,
                              void* d_out, int out_size, void* d_ws, size_t ws_size,
                              hipStream_t stream) {
    const float* x    = (const float*)d_in[0];
    const float* ln1w = (const float*)d_in[1];
    const float* ln1b = (const float*)d_in[2];
    const float* ln2w = (const float*)d_in[3];
    const float* ln2b = (const float*)d_in[4];
    const float* win  = (const float*)d_in[5];   // (1536, 384)
    const float* cw   = (const float*)d_in[6];   // (768, 1, 4)
    const float* cb   = (const float*)d_in[7];   // (768,)
    const float* wxp  = (const float*)d_in[8];   // (56, 768)
    const float* wdt  = (const float*)d_in[9];   // (768, 24)
    const float* bdt  = (const float*)d_in[10];  // (768,)
    const float* alog = (const float*)d_in[11];  // (768, 16)
    const float* Dw   = (const float*)d_in[12];  // (768,)
    const float* wout = (const float*)d_in[13];  // (384, 768)

    char* ws = (char*)d_ws;
    u16*   wbf    = (u16*)(ws + 0);            // 927744 bf16
    u16*   win_b  = wbf + OFFW_WIN;
    u16*   wxp_b  = wbf + OFFW_WXP;
    u16*   wout_b = wbf + OFFW_WOUT;
    u16*   xn     = (u16*)(ws + 1855488);      // 4096*384 bf16
    u16*   xz     = (u16*)(ws + 5001216);      // 4096*1536 bf16
    float* dbc    = (float*)(ws + 17584128);   // 4096*56 f32
    float* chA    = (float*)(ws + 18501632);   // 256 bc * 16*768 f32 (s-major per bc)
    float* chB    = (float*)(ws + 31084544);
    float* hin    = (float*)(ws + 43667456);

    ln1_convert<<<dim3(256), 256, 0, stream>>>(x, ln1w, ln1b, xn, win, wxp, wout, wbf);
    gemm_in<384><<<dim3(32, 12), 256, 0, stream>>>(xn, win_b, xz, DXZ);
    convxp_scan1<<<dim3(256), 768, 0, stream>>>(xz, cw, cb, wxp_b, alog, wdt, bdt, dbc, chA, chB);
    scan_mid<<<96, 256, 0, stream>>>(chA, chB, hin);
    scan2_out_ln2<<<dim3(256), 768, 0, stream>>>(xz, cw, cb, dbc, alog, wdt, bdt, hin, Dw,
                                                 wout_b, x, ln2w, ln2b, (float*)d_out);
}